// Round 1
// baseline (1866.955 us; speedup 1.0000x reference)
//
#include <hip/hip_runtime.h>
#include <hip/hip_bf16.h>
#include <math.h>

#define T_TOK 4096   // B*S
#define H_DIM 2048
#define I_DIM 4096
#define E_NUM 8

typedef __attribute__((ext_vector_type(8))) short short8;
typedef __attribute__((ext_vector_type(4))) float float4v;

// ---------------- ws layout (bytes) ----------------
// 0      : int flag (1 = bf16 storage, 0 = fp32 storage)
// 64     : int counts[8]
// 128    : int offs[8]
// 192    : int cursor[8]
// 1024   : int tkidx[2T]            (32768 B)
// 33792  : float tkw[2T]            (32768 B)
// 66560  : int rowts[2T]            (32768 B)
// 131072 : A2  bf16 [2T][I]         (67108864 B)
// 67239936: buf fp32 [2T][H]        (67108864 B)
// total ~134.4 MB

__device__ __forceinline__ float ldf(const float* p){ return *p; }
__device__ __forceinline__ float ldf(const __hip_bfloat16* p){ return __bfloat162float(*p); }

__device__ __forceinline__ unsigned short f2b(float f){
  union { float f; unsigned u; } v; v.f = f;
  unsigned r = v.u + 0x7fffu + ((v.u >> 16) & 1u);
  return (unsigned short)(r >> 16);
}

__device__ __forceinline__ unsigned short ld1b(const float* p){ return f2b(*p); }
__device__ __forceinline__ unsigned short ld1b(const __hip_bfloat16* p){ return *(const unsigned short*)p; }

__device__ __forceinline__ void ld4b(const float* p, unsigned short* o){
  float4 v = *(const float4*)p;
  o[0]=f2b(v.x); o[1]=f2b(v.y); o[2]=f2b(v.z); o[3]=f2b(v.w);
}
__device__ __forceinline__ void ld4b(const __hip_bfloat16* p, unsigned short* o){
  ushort4 v = *(const ushort4*)p;
  o[0]=v.x; o[1]=v.y; o[2]=v.z; o[3]=v.w;
}

// ---------------- dtype detect ----------------
__global__ __launch_bounds__(64) void k_detect(const unsigned* __restrict__ x, int* flag){
  int cnt = 0;
  for (int i = threadIdx.x; i < 512; i += 64){
    unsigned u  = x[i];
    unsigned lo = u & 0xffffu;          // bf16 elem 2i if bf16 storage; random mantissa if fp32
    unsigned ex = (lo >> 7) & 0xffu;
    if ((lo & 0x7fffu) == 0u || (ex >= 0x70u && ex <= 0x82u)) cnt++;
  }
  for (int off = 32; off > 0; off >>= 1) cnt += __shfl_down(cnt, off);
  if (threadIdx.x == 0) *flag = (cnt > 256) ? 1 : 0;
}

// ---------------- router ----------------
template<typename T>
__device__ __forceinline__ void router_body(const T* __restrict__ x, const T* __restrict__ gw,
    void* out, int is_bf, int* counts, int* tkidx, float* tkw)
{
  int t = blockIdx.x;
  int lane = threadIdx.x;
  float acc[E_NUM];
  #pragma unroll
  for (int e=0;e<E_NUM;++e) acc[e]=0.f;
  const T* xr = x + (size_t)t*H_DIM;
  for (int h = lane; h < H_DIM; h += 64){
    float xv = ldf(xr + h);
    #pragma unroll
    for (int e=0;e<E_NUM;++e) acc[e] += xv * ldf(gw + h*E_NUM + e);
  }
  #pragma unroll
  for (int off = 32; off > 0; off >>= 1){
    #pragma unroll
    for (int e=0;e<E_NUM;++e) acc[e] += __shfl_down(acc[e], off);
  }
  if (lane == 0){
    int i0 = 0; float v0 = acc[0];
    #pragma unroll
    for (int e=1;e<E_NUM;++e) if (acc[e] > v0){ v0 = acc[e]; i0 = e; }
    int i1 = -1; float v1 = -3.4e38f;
    #pragma unroll
    for (int e=0;e<E_NUM;++e) if (e != i0 && acc[e] > v1){ v1 = acc[e]; i1 = e; }
    float ex  = expf(v1 - v0);
    float inv = 1.f/(1.f + ex);
    tkidx[2*t]   = i0; tkidx[2*t+1] = i1;
    tkw[2*t]     = inv; tkw[2*t+1]  = ex*inv;
    atomicAdd(&counts[i0], 1); atomicAdd(&counts[i1], 1);
    if (is_bf){
      unsigned short* o = (unsigned short*)out + (size_t)T_TOK*H_DIM + (size_t)t*E_NUM;
      #pragma unroll
      for (int e=0;e<E_NUM;++e) o[e] = f2b(acc[e]);
    } else {
      float* o = (float*)out + (size_t)T_TOK*H_DIM + (size_t)t*E_NUM;
      #pragma unroll
      for (int e=0;e<E_NUM;++e) o[e] = acc[e];
    }
  }
}

__global__ __launch_bounds__(64) void k_router(const int* flag, const void* x, const void* gw,
    void* out, int* counts, int* tkidx, float* tkw){
  if (*flag) router_body((const __hip_bfloat16*)x, (const __hip_bfloat16*)gw, out, 1, counts, tkidx, tkw);
  else       router_body((const float*)x,          (const float*)gw,          out, 0, counts, tkidx, tkw);
}

__global__ void k_offsets(const int* counts, int* offs){
  if (threadIdx.x == 0){
    int s = 0;
    for (int e=0;e<E_NUM;++e){ offs[e] = s; s += counts[e]; }
  }
}

__global__ __launch_bounds__(256) void k_assign(const int* __restrict__ tkidx, const int* __restrict__ offs,
    int* cursor, int* __restrict__ rowts){
  int t = blockIdx.x*256 + threadIdx.x;
  if (t < T_TOK){
    #pragma unroll
    for (int s=0;s<2;++s){
      int e = tkidx[2*t+s];
      int p = atomicAdd(&cursor[e], 1);
      rowts[offs[e] + p] = t*2 + s;
    }
  }
}

// ---------------- GEMM tiles ----------------
#define BM 128
#define BN 64
#define BK 64
#define LDK 72   // BK + 8 bf16 pad: conflict-free b128 fragment reads

template<typename T>
__device__ __forceinline__ void gemm1_body(
    const T* __restrict__ x, const T* __restrict__ gp, const T* __restrict__ up,
    unsigned short* __restrict__ A2,
    const int* __restrict__ counts, const int* __restrict__ offs, const int* __restrict__ rowts)
{
  __shared__ unsigned short sA[BM*LDK];
  __shared__ unsigned short sG[BN*LDK];
  __shared__ unsigned short sU[BN*LDK];
  __shared__ int sTok[BM];

  const int e   = blockIdx.z;
  const int cnt = counts[e];
  const int m0  = blockIdx.y * BM;
  if (m0 >= cnt) return;
  const int n0    = blockIdx.x * BN;
  const int offsE = offs[e];
  const int tid   = threadIdx.x;

  if (tid < BM){
    int r  = m0 + tid;
    int ts = rowts[offsE + ((r < cnt) ? r : 0)];
    sTok[tid] = ts >> 1;
  }
  __syncthreads();

  const T* __restrict__ G = gp + (size_t)e * H_DIM * I_DIM;
  const T* __restrict__ U = up + (size_t)e * H_DIM * I_DIM;

  float4v accg[4][2], accu[4][2];
  #pragma unroll
  for (int i=0;i<4;++i)
    #pragma unroll
    for (int j=0;j<2;++j){ accg[i][j] = (float4v){0.f,0.f,0.f,0.f}; accu[i][j] = (float4v){0.f,0.f,0.f,0.f}; }

  const int lane = tid & 63;
  const int wid  = tid >> 6;
  const int wm = wid & 1, wn = wid >> 1;
  const int quad = lane >> 4, cL = lane & 15;

  const int a_m   = tid >> 4;          // 0..15
  const int a_kc  = (tid & 15) * 4;    // 0..60
  const int b_n   = tid & 63;
  const int b_kc0 = tid >> 6;          // 0..3

  for (int k0 = 0; k0 < H_DIM; k0 += BK){
    // stage A (gathered token rows), convert to bf16
    #pragma unroll
    for (int it = 0; it < 8; ++it){
      int m = a_m + it*16;
      const T* src = x + (size_t)sTok[m]*H_DIM + (k0 + a_kc);
      unsigned short tmp[4];
      ld4b(src, tmp);
      ushort4 v; v.x=tmp[0]; v.y=tmp[1]; v.z=tmp[2]; v.w=tmp[3];
      *(ushort4*)(&sA[m*LDK + a_kc]) = v;
    }
    // stage B transposed: sG[n][k], sU[n][k]
    #pragma unroll
    for (int half = 0; half < 2; ++half){
      int kc = b_kc0 + half*4;                       // 0..7
      size_t base = (size_t)(k0 + kc*8) * I_DIM + (size_t)(n0 + b_n);
      short8 vg, vu;
      #pragma unroll
      for (int j=0;j<8;++j){
        vg[j] = (short)ld1b(G + base + (size_t)j*I_DIM);
        vu[j] = (short)ld1b(U + base + (size_t)j*I_DIM);
      }
      *(short8*)(&sG[b_n*LDK + kc*8]) = vg;
      *(short8*)(&sU[b_n*LDK + kc*8]) = vu;
    }
    __syncthreads();
    #pragma unroll
    for (int kb = 0; kb < BK; kb += 32){
      short8 af[4];
      #pragma unroll
      for (int mt=0; mt<4; ++mt)
        af[mt] = *(const short8*)(&sA[(wm*64 + mt*16 + cL)*LDK + kb + quad*8]);
      short8 bg[2], bu[2];
      #pragma unroll
      for (int nt=0; nt<2; ++nt){
        bg[nt] = *(const short8*)(&sG[(wn*32 + nt*16 + cL)*LDK + kb + quad*8]);
        bu[nt] = *(const short8*)(&sU[(wn*32 + nt*16 + cL)*LDK + kb + quad*8]);
      }
      #pragma unroll
      for (int mt=0; mt<4; ++mt)
        #pragma unroll
        for (int nt=0; nt<2; ++nt){
          accg[mt][nt] = __builtin_amdgcn_mfma_f32_16x16x32_bf16(af[mt], bg[nt], accg[mt][nt], 0, 0, 0);
          accu[mt][nt] = __builtin_amdgcn_mfma_f32_16x16x32_bf16(af[mt], bu[nt], accu[mt][nt], 0, 0, 0);
        }
    }
    __syncthreads();
  }
  // epilogue: a = gelu(g)*u  -> A2 (bf16)
  #pragma unroll
  for (int mt=0; mt<4; ++mt){
    int rb = m0 + wm*64 + mt*16 + quad*4;
    #pragma unroll
    for (int nt=0; nt<2; ++nt){
      int col = n0 + wn*32 + nt*16 + cL;
      #pragma unroll
      for (int r=0; r<4; ++r){
        int row = rb + r;
        if (row < cnt){
          float g = accg[mt][nt][r];
          float u = accu[mt][nt][r];
          float t3 = g * (1.f + 0.044715f * g * g);
          float gl = 0.5f * g * (1.f + tanhf(0.7978845608028654f * t3));
          A2[(size_t)(offsE + row)*I_DIM + col] = f2b(gl * u);
        }
      }
    }
  }
}

__global__ __launch_bounds__(256, 2) void k_gemm1(const int* flag, const void* x, const void* gp,
    const void* up, unsigned short* A2, const int* counts, const int* offs, const int* rowts){
  if (*flag) gemm1_body((const __hip_bfloat16*)x, (const __hip_bfloat16*)gp, (const __hip_bfloat16*)up, A2, counts, offs, rowts);
  else       gemm1_body((const float*)x,          (const float*)gp,          (const float*)up,          A2, counts, offs, rowts);
}

template<typename T>
__device__ __forceinline__ void gemm2_body(
    const unsigned short* __restrict__ A2, const T* __restrict__ dp, float* __restrict__ buf,
    const int* __restrict__ counts, const int* __restrict__ offs, const int* __restrict__ rowts)
{
  __shared__ unsigned short sA[BM*LDK];
  __shared__ unsigned short sB[BN*LDK];

  const int e   = blockIdx.z;
  const int cnt = counts[e];
  const int m0  = blockIdx.y * BM;
  if (m0 >= cnt) return;
  const int n0    = blockIdx.x * BN;
  const int offsE = offs[e];
  const int tid   = threadIdx.x;

  const T* __restrict__ D = dp + (size_t)e * I_DIM * H_DIM;

  float4v acc[4][2];
  #pragma unroll
  for (int i=0;i<4;++i)
    #pragma unroll
    for (int j=0;j<2;++j) acc[i][j] = (float4v){0.f,0.f,0.f,0.f};

  const int lane = tid & 63;
  const int wid  = tid >> 6;
  const int wm = wid & 1, wn = wid >> 1;
  const int quad = lane >> 4, cL = lane & 15;

  const int a_m   = tid >> 4;
  const int a_kc  = (tid & 15) * 4;
  const int b_n   = tid & 63;
  const int b_kc0 = tid >> 6;

  for (int k0 = 0; k0 < I_DIM; k0 += BK){
    #pragma unroll
    for (int it = 0; it < 8; ++it){
      int m = a_m + it*16;
      int row = m0 + m; if (row >= cnt) row = cnt - 1;
      const unsigned short* src = A2 + (size_t)(offsE + row)*I_DIM + (k0 + a_kc);
      *(ushort4*)(&sA[m*LDK + a_kc]) = *(const ushort4*)src;
    }
    #pragma unroll
    for (int half = 0; half < 2; ++half){
      int kc = b_kc0 + half*4;
      size_t base = (size_t)(k0 + kc*8) * H_DIM + (size_t)(n0 + b_n);
      short8 vb;
      #pragma unroll
      for (int j=0;j<8;++j) vb[j] = (short)ld1b(D + base + (size_t)j*H_DIM);
      *(short8*)(&sB[b_n*LDK + kc*8]) = vb;
    }
    __syncthreads();
    #pragma unroll
    for (int kb = 0; kb < BK; kb += 32){
      short8 af[4];
      #pragma unroll
      for (int mt=0; mt<4; ++mt)
        af[mt] = *(const short8*)(&sA[(wm*64 + mt*16 + cL)*LDK + kb + quad*8]);
      short8 bb[2];
      #pragma unroll
      for (int nt=0; nt<2; ++nt)
        bb[nt] = *(const short8*)(&sB[(wn*32 + nt*16 + cL)*LDK + kb + quad*8]);
      #pragma unroll
      for (int mt=0; mt<4; ++mt)
        #pragma unroll
        for (int nt=0; nt<2; ++nt)
          acc[mt][nt] = __builtin_amdgcn_mfma_f32_16x16x32_bf16(af[mt], bb[nt], acc[mt][nt], 0, 0, 0);
    }
    __syncthreads();
  }
  // epilogue: scatter rows to per-(token,slot) buffer (unweighted, fp32)
  #pragma unroll
  for (int mt=0; mt<4; ++mt){
    int rb = m0 + wm*64 + mt*16 + quad*4;
    #pragma unroll
    for (int nt=0; nt<2; ++nt){
      int col = n0 + wn*32 + nt*16 + cL;
      #pragma unroll
      for (int r=0; r<4; ++r){
        int row = rb + r;
        if (row < cnt){
          int ts = rowts[offsE + row];
          buf[(size_t)ts*H_DIM + col] = acc[mt][nt][r];
        }
      }
    }
  }
}

__global__ __launch_bounds__(256, 2) void k_gemm2(const int* flag, const unsigned short* A2,
    const void* dp, float* buf, const int* counts, const int* offs, const int* rowts){
  if (*flag) gemm2_body(A2, (const __hip_bfloat16*)dp, buf, counts, offs, rowts);
  else       gemm2_body(A2, (const float*)dp,          buf, counts, offs, rowts);
}

// ---------------- combine ----------------
__global__ __launch_bounds__(256) void k_combine(const int* flag, const float* __restrict__ buf,
    const float* __restrict__ tkw, void* out)
{
  int idx = blockIdx.x*256 + threadIdx.x;   // over T_TOK * (H_DIM/4)
  int t = idx >> 9;                          // H_DIM/4 = 512
  int c = idx & 511;
  float w0 = tkw[2*t], w1 = tkw[2*t+1];
  const float4* b4 = (const float4*)buf;
  float4 a = b4[((size_t)t*2)*512 + c];
  float4 b = b4[((size_t)t*2+1)*512 + c];
  float r0 = w0*a.x + w1*b.x;
  float r1 = w0*a.y + w1*b.y;
  float r2 = w0*a.z + w1*b.z;
  float r3 = w0*a.w + w1*b.w;
  if (*flag){
    ushort4 v; v.x=f2b(r0); v.y=f2b(r1); v.z=f2b(r2); v.w=f2b(r3);
    *(ushort4*)((unsigned short*)out + (size_t)t*H_DIM + c*4) = v;
  } else {
    float4 v; v.x=r0; v.y=r1; v.z=r2; v.w=r3;
    *(float4*)((float*)out + (size_t)t*H_DIM + c*4) = v;
  }
}

extern "C" void kernel_launch(void* const* d_in, const int* in_sizes, int n_in,
                              void* d_out, int out_size, void* d_ws, size_t ws_size,
                              hipStream_t stream)
{
  (void)in_sizes; (void)n_in; (void)out_size; (void)ws_size;
  const void* x  = d_in[0];
  const void* gw = d_in[1];
  const void* gp = d_in[2];
  const void* up = d_in[3];
  const void* dp = d_in[4];

  char* w = (char*)d_ws;
  int*   flag   = (int*)(w + 0);
  int*   counts = (int*)(w + 64);
  int*   offs   = (int*)(w + 128);
  int*   cursor = (int*)(w + 192);
  int*   tkidx  = (int*)(w + 1024);
  float* tkw    = (float*)(w + 1024 + 32768);
  int*   rowts  = (int*)(w + 1024 + 65536);
  unsigned short* A2 = (unsigned short*)(w + 131072);
  float* buf    = (float*)(w + 131072 + 67108864);

  hipMemsetAsync(counts, 0, 192, stream);   // counts + offs + cursor

  k_detect <<<1, 64, 0, stream>>>((const unsigned*)x, flag);
  k_router <<<T_TOK, 64, 0, stream>>>(flag, x, gw, d_out, counts, tkidx, tkw);
  k_offsets<<<1, 64, 0, stream>>>(counts, offs);
  k_assign <<<T_TOK/256, 256, 0, stream>>>(tkidx, offs, cursor, rowts);
  k_gemm1  <<<dim3(I_DIM/BN, 32, E_NUM), 256, 0, stream>>>(flag, x, gp, up, A2, counts, offs, rowts);
  k_gemm2  <<<dim3(H_DIM/BN, 32, E_NUM), 256, 0, stream>>>(flag, A2, dp, buf, counts, offs, rowts);
  k_combine<<<(T_TOK*512)/256, 256, 0, stream>>>(flag, buf, tkw, d_out);
}

// Round 2
// 1753.879 us; speedup vs baseline: 1.0645x; 1.0645x over previous
//
#include <hip/hip_runtime.h>
#include <hip/hip_bf16.h>
#include <math.h>

#define T_TOK 4096   // B*S
#define H_DIM 2048
#define I_DIM 4096
#define E_NUM 8

typedef __attribute__((ext_vector_type(8))) short short8;
typedef __attribute__((ext_vector_type(8))) unsigned short ushort8v;
typedef __attribute__((ext_vector_type(4))) float float4v;

// ---------------- ws layout (bytes) ----------------
// 0      : int flag (1 = bf16 storage, 0 = fp32 storage)
// 64     : int counts[8]
// 128    : int offs[8]
// 192    : int cursor[8]
// 1024   : int tkidx[2T]            (32768 B)
// 33792  : float tkw[2T]            (32768 B)
// 66560  : int rowts[2T]            (32768 B)
// 131072 : A2  bf16 [2T][I]         (67108864 B)
// 67239936: buf fp32 [2T][H]        (67108864 B)

__device__ __forceinline__ float ldf(const float* p){ return *p; }
__device__ __forceinline__ float ldf(const __hip_bfloat16* p){ return __bfloat162float(*p); }

__device__ __forceinline__ unsigned short f2b(float f){
  union { float f; unsigned u; } v; v.f = f;
  unsigned r = v.u + 0x7fffu + ((v.u >> 16) & 1u);
  return (unsigned short)(r >> 16);
}

// load 8 consecutive elements as bf16 bits
__device__ __forceinline__ ushort8v ld8b(const __hip_bfloat16* p){
  return *(const ushort8v*)p;
}
__device__ __forceinline__ ushort8v ld8b(const float* p){
  float4 a = *(const float4*)p;
  float4 b = *(const float4*)(p + 4);
  ushort8v r;
  r[0]=f2b(a.x); r[1]=f2b(a.y); r[2]=f2b(a.z); r[3]=f2b(a.w);
  r[4]=f2b(b.x); r[5]=f2b(b.y); r[6]=f2b(b.z); r[7]=f2b(b.w);
  return r;
}

// ---------------- dtype detect ----------------
__global__ __launch_bounds__(64) void k_detect(const unsigned* __restrict__ x, int* flag){
  int cnt = 0;
  for (int i = threadIdx.x; i < 512; i += 64){
    unsigned u  = x[i];
    unsigned lo = u & 0xffffu;
    unsigned ex = (lo >> 7) & 0xffu;
    if ((lo & 0x7fffu) == 0u || (ex >= 0x70u && ex <= 0x82u)) cnt++;
  }
  for (int off = 32; off > 0; off >>= 1) cnt += __shfl_down(cnt, off);
  if (threadIdx.x == 0) *flag = (cnt > 256) ? 1 : 0;
}

// ---------------- router ----------------
template<typename T>
__device__ __forceinline__ void router_body(const T* __restrict__ x, const T* __restrict__ gw,
    void* out, int is_bf, int* counts, int* tkidx, float* tkw)
{
  int t = blockIdx.x;
  int lane = threadIdx.x;
  float acc[E_NUM];
  #pragma unroll
  for (int e=0;e<E_NUM;++e) acc[e]=0.f;
  const T* xr = x + (size_t)t*H_DIM;
  for (int h = lane; h < H_DIM; h += 64){
    float xv = ldf(xr + h);
    #pragma unroll
    for (int e=0;e<E_NUM;++e) acc[e] += xv * ldf(gw + h*E_NUM + e);
  }
  #pragma unroll
  for (int off = 32; off > 0; off >>= 1){
    #pragma unroll
    for (int e=0;e<E_NUM;++e) acc[e] += __shfl_down(acc[e], off);
  }
  if (lane == 0){
    int i0 = 0; float v0 = acc[0];
    #pragma unroll
    for (int e=1;e<E_NUM;++e) if (acc[e] > v0){ v0 = acc[e]; i0 = e; }
    int i1 = -1; float v1 = -3.4e38f;
    #pragma unroll
    for (int e=0;e<E_NUM;++e) if (e != i0 && acc[e] > v1){ v1 = acc[e]; i1 = e; }
    float ex  = expf(v1 - v0);
    float inv = 1.f/(1.f + ex);
    tkidx[2*t]   = i0; tkidx[2*t+1] = i1;
    tkw[2*t]     = inv; tkw[2*t+1]  = ex*inv;
    atomicAdd(&counts[i0], 1); atomicAdd(&counts[i1], 1);
    if (is_bf){
      unsigned short* o = (unsigned short*)out + (size_t)T_TOK*H_DIM + (size_t)t*E_NUM;
      #pragma unroll
      for (int e=0;e<E_NUM;++e) o[e] = f2b(acc[e]);
    } else {
      float* o = (float*)out + (size_t)T_TOK*H_DIM + (size_t)t*E_NUM;
      #pragma unroll
      for (int e=0;e<E_NUM;++e) o[e] = acc[e];
    }
  }
}

__global__ __launch_bounds__(64) void k_router(const int* flag, const void* x, const void* gw,
    void* out, int* counts, int* tkidx, float* tkw){
  if (*flag) router_body((const __hip_bfloat16*)x, (const __hip_bfloat16*)gw, out, 1, counts, tkidx, tkw);
  else       router_body((const float*)x,          (const float*)gw,          out, 0, counts, tkidx, tkw);
}

__global__ void k_offsets(const int* counts, int* offs){
  if (threadIdx.x == 0){
    int s = 0;
    for (int e=0;e<E_NUM;++e){ offs[e] = s; s += counts[e]; }
  }
}

__global__ __launch_bounds__(256) void k_assign(const int* __restrict__ tkidx, const int* __restrict__ offs,
    int* cursor, int* __restrict__ rowts){
  int t = blockIdx.x*256 + threadIdx.x;
  if (t < T_TOK){
    #pragma unroll
    for (int s=0;s<2;++s){
      int e = tkidx[2*t+s];
      int p = atomicAdd(&cursor[e], 1);
      rowts[offs[e] + p] = t*2 + s;
    }
  }
}

// ---------------- GEMM tiles ----------------
#define BM 128
#define BN 64
#define BK 64
#define LDK 72   // BK + 8 bf16 pad

// XOR swizzle (in shorts) for transposed B tiles: k' = k ^ ((n>>3 & 7)<<3)
__device__ __forceinline__ int bswz(int n, int k){ return k ^ (((n >> 3) & 7) << 3); }

// Stage one BKxBN natural-layout [k][n] global tile into LDS as [n][k] (swizzled).
// Thread mapping: q = tid>>3 (k-pair 0..31), c8 = (tid&7)*8 (n chunk).
template<typename T>
__device__ __forceinline__ void stage_bT(const T* __restrict__ src, size_t ld,
    unsigned short* __restrict__ sB, int q, int c8)
{
  const T* p0 = src + (size_t)(2*q)*ld + c8;
  ushort8v r0 = ld8b(p0);
  ushort8v r1 = ld8b(p0 + ld);
  #pragma unroll
  for (int j=0;j<8;++j){
    int n = c8 + j;
    int ks = bswz(n, 2*q);
    *(unsigned*)(&sB[n*LDK + ks]) = (unsigned)r0[j] | ((unsigned)r1[j] << 16);
  }
}

template<typename T>
__device__ __forceinline__ void gemm1_body(
    const T* __restrict__ x, const T* __restrict__ gp, const T* __restrict__ up,
    unsigned short* __restrict__ A2,
    const int* __restrict__ counts, const int* __restrict__ offs, const int* __restrict__ rowts)
{
  __shared__ unsigned short sA[BM*LDK];
  __shared__ unsigned short sG[BN*LDK];
  __shared__ unsigned short sU[BN*LDK];
  __shared__ int sTok[BM];

  const int e   = blockIdx.z;
  const int cnt = counts[e];
  const int m0  = blockIdx.y * BM;
  if (m0 >= cnt) return;
  const int n0    = blockIdx.x * BN;
  const int offsE = offs[e];
  const int tid   = threadIdx.x;

  if (tid < BM){
    int r  = m0 + tid;
    int ts = rowts[offsE + ((r < cnt) ? r : 0)];
    sTok[tid] = ts >> 1;
  }
  __syncthreads();

  const T* __restrict__ G = gp + (size_t)e * H_DIM * I_DIM;
  const T* __restrict__ U = up + (size_t)e * H_DIM * I_DIM;

  float4v accg[4][2], accu[4][2];
  #pragma unroll
  for (int i=0;i<4;++i)
    #pragma unroll
    for (int j=0;j<2;++j){ accg[i][j] = (float4v){0.f,0.f,0.f,0.f}; accu[i][j] = (float4v){0.f,0.f,0.f,0.f}; }

  const int lane = tid & 63;
  const int wid  = tid >> 6;
  const int wm = wid & 1, wn = wid >> 1;
  const int quad = lane >> 4, cL = lane & 15;

  const int ar  = tid >> 3;        // 0..31 (A row group)
  const int akc = (tid & 7) * 8;   // 0..56 (A k chunk)
  const int q   = tid >> 3;        // 0..31 (B k-pair)
  const int c8  = (tid & 7) * 8;   // B n chunk

  for (int k0 = 0; k0 < H_DIM; k0 += BK){
    // stage A (gathered token rows), 16B-wide
    #pragma unroll
    for (int it = 0; it < 4; ++it){
      int m = ar + it*32;
      const T* src = x + (size_t)sTok[m]*H_DIM + (k0 + akc);
      ushort8v v = ld8b(src);
      *(ushort8v*)(&sA[m*LDK + akc]) = v;
    }
    // stage B (natural [k][n] loads, swizzled LDS transpose)
    stage_bT(G + (size_t)k0*I_DIM + n0, I_DIM, sG, q, c8);
    stage_bT(U + (size_t)k0*I_DIM + n0, I_DIM, sU, q, c8);
    __syncthreads();
    #pragma unroll
    for (int kb = 0; kb < BK; kb += 32){
      short8 af[4];
      #pragma unroll
      for (int mt=0; mt<4; ++mt)
        af[mt] = *(const short8*)(&sA[(wm*64 + mt*16 + cL)*LDK + kb + quad*8]);
      short8 bg[2], bu[2];
      #pragma unroll
      for (int nt=0; nt<2; ++nt){
        int n = wn*32 + nt*16 + cL;
        int ks = bswz(n, kb + quad*8);
        bg[nt] = *(const short8*)(&sG[n*LDK + ks]);
        bu[nt] = *(const short8*)(&sU[n*LDK + ks]);
      }
      #pragma unroll
      for (int mt=0; mt<4; ++mt)
        #pragma unroll
        for (int nt=0; nt<2; ++nt){
          accg[mt][nt] = __builtin_amdgcn_mfma_f32_16x16x32_bf16(af[mt], bg[nt], accg[mt][nt], 0, 0, 0);
          accu[mt][nt] = __builtin_amdgcn_mfma_f32_16x16x32_bf16(af[mt], bu[nt], accu[mt][nt], 0, 0, 0);
        }
    }
    __syncthreads();
  }
  // epilogue: a = gelu(g)*u  -> A2 (bf16)
  #pragma unroll
  for (int mt=0; mt<4; ++mt){
    int rb = m0 + wm*64 + mt*16 + quad*4;
    #pragma unroll
    for (int nt=0; nt<2; ++nt){
      int col = n0 + wn*32 + nt*16 + cL;
      #pragma unroll
      for (int r=0; r<4; ++r){
        int row = rb + r;
        if (row < cnt){
          float g = accg[mt][nt][r];
          float u = accu[mt][nt][r];
          float t3 = g * (1.f + 0.044715f * g * g);
          float gl = 0.5f * g * (1.f + tanhf(0.7978845608028654f * t3));
          A2[(size_t)(offsE + row)*I_DIM + col] = f2b(gl * u);
        }
      }
    }
  }
}

__global__ __launch_bounds__(256, 2) void k_gemm1(const int* flag, const void* x, const void* gp,
    const void* up, unsigned short* A2, const int* counts, const int* offs, const int* rowts){
  if (*flag) gemm1_body((const __hip_bfloat16*)x, (const __hip_bfloat16*)gp, (const __hip_bfloat16*)up, A2, counts, offs, rowts);
  else       gemm1_body((const float*)x,          (const float*)gp,          (const float*)up,          A2, counts, offs, rowts);
}

template<typename T>
__device__ __forceinline__ void gemm2_body(
    const unsigned short* __restrict__ A2, const T* __restrict__ dp, float* __restrict__ buf,
    const int* __restrict__ counts, const int* __restrict__ offs, const int* __restrict__ rowts)
{
  __shared__ unsigned short sA[BM*LDK];
  __shared__ unsigned short sB[BN*LDK];

  const int e   = blockIdx.z;
  const int cnt = counts[e];
  const int m0  = blockIdx.y * BM;
  if (m0 >= cnt) return;
  const int n0    = blockIdx.x * BN;
  const int offsE = offs[e];
  const int tid   = threadIdx.x;

  const T* __restrict__ D = dp + (size_t)e * I_DIM * H_DIM;

  float4v acc[4][2];
  #pragma unroll
  for (int i=0;i<4;++i)
    #pragma unroll
    for (int j=0;j<2;++j) acc[i][j] = (float4v){0.f,0.f,0.f,0.f};

  const int lane = tid & 63;
  const int wid  = tid >> 6;
  const int wm = wid & 1, wn = wid >> 1;
  const int quad = lane >> 4, cL = lane & 15;

  const int ar  = tid >> 3;
  const int akc = (tid & 7) * 8;
  const int q   = tid >> 3;
  const int c8  = (tid & 7) * 8;

  for (int k0 = 0; k0 < I_DIM; k0 += BK){
    #pragma unroll
    for (int it = 0; it < 4; ++it){
      int m = ar + it*32;
      int row = m0 + m; if (row >= cnt) row = cnt - 1;
      const unsigned short* src = A2 + (size_t)(offsE + row)*I_DIM + (k0 + akc);
      *(ushort8v*)(&sA[m*LDK + akc]) = *(const ushort8v*)src;
    }
    stage_bT(D + (size_t)k0*H_DIM + n0, H_DIM, sB, q, c8);
    __syncthreads();
    #pragma unroll
    for (int kb = 0; kb < BK; kb += 32){
      short8 af[4];
      #pragma unroll
      for (int mt=0; mt<4; ++mt)
        af[mt] = *(const short8*)(&sA[(wm*64 + mt*16 + cL)*LDK + kb + quad*8]);
      short8 bb[2];
      #pragma unroll
      for (int nt=0; nt<2; ++nt){
        int n = wn*32 + nt*16 + cL;
        int ks = bswz(n, kb + quad*8);
        bb[nt] = *(const short8*)(&sB[n*LDK + ks]);
      }
      #pragma unroll
      for (int mt=0; mt<4; ++mt)
        #pragma unroll
        for (int nt=0; nt<2; ++nt)
          acc[mt][nt] = __builtin_amdgcn_mfma_f32_16x16x32_bf16(af[mt], bb[nt], acc[mt][nt], 0, 0, 0);
    }
    __syncthreads();
  }
  // epilogue: scatter rows to per-(token,slot) buffer (unweighted, fp32)
  #pragma unroll
  for (int mt=0; mt<4; ++mt){
    int rb = m0 + wm*64 + mt*16 + quad*4;
    #pragma unroll
    for (int nt=0; nt<2; ++nt){
      int col = n0 + wn*32 + nt*16 + cL;
      #pragma unroll
      for (int r=0; r<4; ++r){
        int row = rb + r;
        if (row < cnt){
          int ts = rowts[offsE + row];
          buf[(size_t)ts*H_DIM + col] = acc[mt][nt][r];
        }
      }
    }
  }
}

__global__ __launch_bounds__(256, 2) void k_gemm2(const int* flag, const unsigned short* A2,
    const void* dp, float* buf, const int* counts, const int* offs, const int* rowts){
  if (*flag) gemm2_body(A2, (const __hip_bfloat16*)dp, buf, counts, offs, rowts);
  else       gemm2_body(A2, (const float*)dp,          buf, counts, offs, rowts);
}

// ---------------- combine ----------------
__global__ __launch_bounds__(256) void k_combine(const int* flag, const float* __restrict__ buf,
    const float* __restrict__ tkw, void* out)
{
  int idx = blockIdx.x*256 + threadIdx.x;   // over T_TOK * (H_DIM/4)
  int t = idx >> 9;                          // H_DIM/4 = 512
  int c = idx & 511;
  float w0 = tkw[2*t], w1 = tkw[2*t+1];
  const float4* b4 = (const float4*)buf;
  float4 a = b4[((size_t)t*2)*512 + c];
  float4 b = b4[((size_t)t*2+1)*512 + c];
  float r0 = w0*a.x + w1*b.x;
  float r1 = w0*a.y + w1*b.y;
  float r2 = w0*a.z + w1*b.z;
  float r3 = w0*a.w + w1*b.w;
  if (*flag){
    ushort4 v; v.x=f2b(r0); v.y=f2b(r1); v.z=f2b(r2); v.w=f2b(r3);
    *(ushort4*)((unsigned short*)out + (size_t)t*H_DIM + c*4) = v;
  } else {
    float4 v; v.x=r0; v.y=r1; v.z=r2; v.w=r3;
    *(float4*)((float*)out + (size_t)t*H_DIM + c*4) = v;
  }
}

extern "C" void kernel_launch(void* const* d_in, const int* in_sizes, int n_in,
                              void* d_out, int out_size, void* d_ws, size_t ws_size,
                              hipStream_t stream)
{
  (void)in_sizes; (void)n_in; (void)out_size; (void)ws_size;
  const void* x  = d_in[0];
  const void* gw = d_in[1];
  const void* gp = d_in[2];
  const void* up = d_in[3];
  const void* dp = d_in[4];

  char* w = (char*)d_ws;
  int*   flag   = (int*)(w + 0);
  int*   counts = (int*)(w + 64);
  int*   offs   = (int*)(w + 128);
  int*   cursor = (int*)(w + 192);
  int*   tkidx  = (int*)(w + 1024);
  float* tkw    = (float*)(w + 1024 + 32768);
  int*   rowts  = (int*)(w + 1024 + 65536);
  unsigned short* A2 = (unsigned short*)(w + 131072);
  float* buf    = (float*)(w + 131072 + 67108864);

  hipMemsetAsync(counts, 0, 192, stream);   // counts + offs + cursor

  k_detect <<<1, 64, 0, stream>>>((const unsigned*)x, flag);
  k_router <<<T_TOK, 64, 0, stream>>>(flag, x, gw, d_out, counts, tkidx, tkw);
  k_offsets<<<1, 64, 0, stream>>>(counts, offs);
  k_assign <<<T_TOK/256, 256, 0, stream>>>(tkidx, offs, cursor, rowts);
  k_gemm1  <<<dim3(I_DIM/BN, 32, E_NUM), 256, 0, stream>>>(flag, x, gp, up, A2, counts, offs, rowts);
  k_gemm2  <<<dim3(H_DIM/BN, 32, E_NUM), 256, 0, stream>>>(flag, A2, dp, buf, counts, offs, rowts);
  k_combine<<<(T_TOK*512)/256, 256, 0, stream>>>(flag, buf, tkw, d_out);
}